// Round 10
// baseline (480.918 us; speedup 1.0000x reference)
//
#include <hip/hip_runtime.h>

// out = tanh(((LN(z) @ W + b) * scale)/3)*3
// z (16384,1024) f32, W (1024,4096) f32, out (16384,4096) f32.
// Internal: zn and Wt in bf16 for MFMA (no fp32 MFMA on CDNA4).
#define M_DIM 16384
#define K_DIM 1024
#define N_DIM 4096
#define T_TILES (K_DIM / 32)   // 32 K-tiles of BK=32

typedef __bf16 bf16x8 __attribute__((ext_vector_type(8)));
typedef float f32x4 __attribute__((ext_vector_type(4)));

__device__ __forceinline__ unsigned short f2bf(float f) {
    union { float f; unsigned int i; } v; v.f = f;
    unsigned int r = v.i + 0x7fffu + ((v.i >> 16) & 1u);  // round-to-nearest-even
    return (unsigned short)(r >> 16);
}
__device__ __forceinline__ unsigned int pack2(float lo, float hi) {
    return ((unsigned int)f2bf(lo)) | (((unsigned int)f2bf(hi)) << 16);
}

// ---------------- Fused prep: LN (blocks [0,4096)) + W transpose (blocks [4096,8192)) ----------------
__global__ __launch_bounds__(256) void prep_kernel(
        const float* __restrict__ z,
        const float* __restrict__ gamma,
        const float* __restrict__ beta,
        unsigned short* __restrict__ zn,
        const float* __restrict__ W,
        unsigned short* __restrict__ Wt) {
    __shared__ float t[32][33];
    const int tid = threadIdx.x;
    if (blockIdx.x < M_DIM / 4) {
        const int wave = tid >> 6;
        const int lane = tid & 63;
        const size_t row = (size_t)blockIdx.x * 4 + wave;
        const float* zr = z + row * K_DIM;

        float4 x[4];
#pragma unroll
        for (int v = 0; v < 4; v++) x[v] = *(const float4*)(zr + v * 256 + lane * 4);

        float s = 0.f, ss = 0.f;
#pragma unroll
        for (int v = 0; v < 4; v++) {
            s  += x[v].x + x[v].y + x[v].z + x[v].w;
            ss += x[v].x * x[v].x + x[v].y * x[v].y + x[v].z * x[v].z + x[v].w * x[v].w;
        }
#pragma unroll
        for (int o = 32; o; o >>= 1) { s += __shfl_xor(s, o, 64); ss += __shfl_xor(ss, o, 64); }
        const float mean = s * (1.f / K_DIM);
        const float var = ss * (1.f / K_DIM) - mean * mean;
        const float rstd = rsqrtf(var + 1e-5f);

#pragma unroll
        for (int v = 0; v < 4; v++) {
            float4 g = *(const float4*)(gamma + v * 256 + lane * 4);
            float4 b = *(const float4*)(beta + v * 256 + lane * 4);
            float o0 = (x[v].x - mean) * rstd * g.x + b.x;
            float o1 = (x[v].y - mean) * rstd * g.y + b.y;
            float o2 = (x[v].z - mean) * rstd * g.z + b.z;
            float o3 = (x[v].w - mean) * rstd * g.w + b.w;
            uint2 q; q.x = pack2(o0, o1); q.y = pack2(o2, o3);
            *(uint2*)(zn + row * K_DIM + v * 256 + lane * 4) = q;
        }
    } else {
        const int bid = blockIdx.x - M_DIM / 4;
        const int tx = tid & 31, ty = tid >> 5;           // (32, 8)
        const int n0 = (bid & (N_DIM / 32 - 1)) * 32, k0 = (bid / (N_DIM / 32)) * 32;
#pragma unroll
        for (int j = 0; j < 32; j += 8)
            t[ty + j][tx] = W[(size_t)(k0 + ty + j) * N_DIM + n0 + tx];
        __syncthreads();
#pragma unroll
        for (int j = 0; j < 32; j += 8)
            Wt[(size_t)(n0 + ty + j) * K_DIM + k0 + tx] = f2bf(t[tx][ty + j]);
    }
}

// ---------------- GEMM: 128x256 tile, 8 waves, ring-3 LDS (72 KB -> 2 blocks/CU), m97-mode ----------------
// Per-wave output 64x64 (acc 64 VGPR); __launch_bounds__(512,4) caps VGPR at 128 -> 4 waves/SIMD,
// TWO blocks resident per CU: one block's LDS-drain/barrier/epilogue hides under the other's MFMAs.
// No sched_barrier, no asm lgkmcnt: compiler emits fine-grained lgkmcnt(N) between ds_read and MFMA
// (m97 mode, 874 TF; m141 showed sched_barrier(0) pinning costs ~40%).
// LDS unit u(row, c in [0,4)) = row*4 + (c ^ ((row>>1)&3)); staging thread tid fetches
// row tid>>2, chunk (tid&3)^((tid>>3)&3) -> linear LDS dest (verified R1/R9, 0 bank conflicts).
// Ring-3, lead-2: top of t stages t+2 into slot (t+2)%3 (its readers finished in t-1, before the
// end-of-(t-1) barrier); end of t: vmcnt(3) retires t+1's 3 loads (keeps t+2's in flight), barrier.
__device__ __forceinline__ void async_copy16(const unsigned short* g, unsigned short* l) {
    __builtin_amdgcn_global_load_lds(
        (const __attribute__((address_space(1))) unsigned int*)g,
        (__attribute__((address_space(3))) unsigned int*)l,
        16, 0, 0);
}

__global__ __launch_bounds__(512, 4) void gemm_kernel(
        const unsigned short* __restrict__ A,   // zn, (M, K) bf16
        const unsigned short* __restrict__ B,   // Wt, (N, K) bf16
        const float* __restrict__ bias,
        const float* __restrict__ scale,
        float* __restrict__ out) {
    __shared__ __align__(16) unsigned short As[3][128 * 32];   // 3 x 8 KB
    __shared__ __align__(16) unsigned short Bs[3][256 * 32];   // 3 x 16 KB  (total 72 KB)

    const int tid = threadIdx.x;
    const int wave = tid >> 6, lane = tid & 63;
    const int wm = wave >> 2, wn = wave & 3;     // 2x4 wave grid, each 64x64 of the 128x256 tile
    const int rl = lane & 15;                    // 16x16 frag row/col index
    const int kc = lane >> 4;                    // k-chunk 0..3
    const int swz = (rl >> 1) & 3;               // layout XOR (row base is a multiple of 16)

    // T1: XCD-aware block swizzle. nwg = 128*16 = 2048, divisible by 8.
    const int bid = blockIdx.y * gridDim.x + blockIdx.x;
    const int id2 = (bid & 7) * 256 + (bid >> 3);
    const int bm = id2 >> 4, bn = id2 & 15;      // bm in [0,128), bn in [0,16)

    // Staging source: thread tid covers unit u = tid (A) and units tid, tid+512 (B).
    const int r0 = tid >> 2;
    const int c0 = ((tid & 3) ^ ((tid >> 3) & 3)) << 3;
    const unsigned short* agA = A + (size_t)(bm * 128 + r0) * K_DIM + c0;
    const unsigned short* agB = B + (size_t)(bn * 256 + r0) * K_DIM + c0;
    const int ldsu = wave * 512;

#define STAGE(t_, s_) do { \
        const unsigned short* gA_ = agA + (t_) * 32; \
        const unsigned short* gB_ = agB + (t_) * 32; \
        async_copy16(gA_,                 &As[s_][ldsu]); \
        async_copy16(gB_,                 &Bs[s_][ldsu]); \
        async_copy16(gB_ + 128 * K_DIM,   &Bs[s_][ldsu + 4096]); } while (0)

    f32x4 acc[4][4] = {};    // [mt][nt] 16x16 tiles; 64 VGPR
    bf16x8 a[4], b[4];

#define READ_A(s_) do { \
        const unsigned short* as_ = As[s_]; \
        _Pragma("unroll") \
        for (int mt_ = 0; mt_ < 4; ++mt_) \
            a[mt_] = *(const bf16x8*)&as_[(wm * 64 + mt_ * 16 + rl) * 32 + ((kc ^ swz) << 3)]; } while (0)
#define READ_B(s_) do { \
        const unsigned short* bs_ = Bs[s_]; \
        _Pragma("unroll") \
        for (int nt_ = 0; nt_ < 4; ++nt_) \
            b[nt_] = *(const bf16x8*)&bs_[(wn * 64 + nt_ * 16 + rl) * 32 + ((kc ^ swz) << 3)]; } while (0)

    // Prologue: stage tiles 0,1 (6 loads); retire tile 0's 3; join.
    STAGE(0, 0);
    STAGE(1, 1);
    asm volatile("s_waitcnt vmcnt(3)" ::: "memory");
    __builtin_amdgcn_s_barrier();
    asm volatile("" ::: "memory");

#pragma unroll
    for (int t = 0; t < T_TILES; ++t) {
        const int s = t % 3;

        if (t + 2 < T_TILES) STAGE(t + 2, (t + 2) % 3);  // slot (t-1)%3: readers done in t-1
        READ_A(s); READ_B(s);                            // compiler inserts fine-grained lgkmcnt

        __builtin_amdgcn_s_setprio(1);
#pragma unroll
        for (int mt = 0; mt < 4; ++mt)
#pragma unroll
            for (int nt = 0; nt < 4; ++nt)
                acc[mt][nt] = __builtin_amdgcn_mfma_f32_16x16x32_bf16(a[mt], b[nt], acc[mt][nt], 0, 0, 0);
        __builtin_amdgcn_s_setprio(0);

        if (t < T_TILES - 2)       asm volatile("s_waitcnt vmcnt(3)" ::: "memory");  // t+1 ready
        else if (t == T_TILES - 2) asm volatile("s_waitcnt vmcnt(0)" ::: "memory");
        if (t < T_TILES - 1) {
            __builtin_amdgcn_s_barrier();
            asm volatile("" ::: "memory");
        }
    }
#undef STAGE
#undef READ_A
#undef READ_B

    // Epilogue: out = 3*tanh(x/3) = 3 - 6/(exp2(x*2/(3 ln2)) + 1); saturates correctly at +-inf.
    // 16x16 C/D layout: col = lane&15, row = (lane>>4)*4 + r  [m89/m91-verified].
    const float mfac = scale[0] * 0.96179669392236f;   // scale * 2/(3*ln2)
#pragma unroll
    for (int nt = 0; nt < 4; ++nt) {
        const int gcol = bn * 256 + wn * 64 + nt * 16 + rl;
        const float bv = bias[gcol];
#pragma unroll
        for (int mt = 0; mt < 4; ++mt) {
            const int rbase = bm * 128 + wm * 64 + mt * 16 + kc * 4;
#pragma unroll
            for (int r = 0; r < 4; ++r) {
                const int grow = rbase + r;
                float tv = (acc[mt][nt][r] + bv) * mfac;
                float e = __builtin_amdgcn_exp2f(tv);
                out[(size_t)grow * N_DIM + gcol] = 3.f - 6.f * __builtin_amdgcn_rcpf(e + 1.f);
            }
        }
    }
}

extern "C" void kernel_launch(void* const* d_in, const int* in_sizes, int n_in,
                              void* d_out, int out_size, void* d_ws, size_t ws_size,
                              hipStream_t stream) {
    const float* z     = (const float*)d_in[0];
    const float* gamma = (const float*)d_in[1];
    const float* beta  = (const float*)d_in[2];
    const float* W     = (const float*)d_in[3];
    const float* b     = (const float*)d_in[4];
    const float* scale = (const float*)d_in[5];
    float* out = (float*)d_out;

    unsigned short* zn = (unsigned short*)d_ws;                 // 16384*1024 bf16 = 32 MB
    unsigned short* Wt = zn + (size_t)M_DIM * K_DIM;            // 4096*1024 bf16  =  8 MB

    prep_kernel<<<M_DIM / 4 + (N_DIM / 32) * (K_DIM / 32), 256, 0, stream>>>(z, gamma, beta, zn, W, Wt);
    gemm_kernel<<<dim3(N_DIM / 256, M_DIM / 128), 512, 0, stream>>>(zn, Wt, b, scale, out);
}